// Round 5
// baseline (1279.765 us; speedup 1.0000x reference)
//
#include <hip/hip_runtime.h>
#include <stdint.h>

#define B_   8
#define T_   1024
#define CIN_ 4096
#define CH_  4096
#define GRP  16              // rows per chase-group (inor->scan and scan->expand)
#define NGRP (T_ / GRP)

// ---- persistent-worker task queue layout ----
#define TK_DETECT 0
#define TK_EXTIN0 1              // 256 tasks: extract A_input, 16 rows each
#define TK_EXTH0  257            // 256 tasks: extract A_hidden
#define TK_INOR0  513            // 1024 tasks: in-OR + z-copy, t = task-513
#define TK_EXP0   1537           // 1024 tasks: h-half expand, t = task-1537
#define TK_END    2561

// flags[]: 0=mode_done 1=extin_ctr 2=exth_ctr | 8+g inor group ctr (->GRP)
//          128+g scan group done (->1) | 200 = task queue counter
#define F_MODE 0
#define F_EXIN 1
#define F_EXH  2
#define F_INOR 8
#define F_SCAN 128
#define F_QCTR 200

// ---------------- helpers ----------------

__device__ __forceinline__ uint32_t bytes_nonzero01(uint32_t w) {
  uint32_t t = (w & 0x7F7F7F7Fu) + 0x7F7F7F7Fu;
  t = (t | w) & 0x80808080u;
  return t >> 7;
}

// load 4 consecutive boolean elements from buffer with element size es; packed 0/1 bytes.
__device__ __forceinline__ uint32_t load4(const void* base, long idx4, int es) {
  if (es == 1) {
    uint32_t w = ((const uint32_t*)base)[idx4];
    return bytes_nonzero01(w);
  } else if (es == 2) {
    uint32_t w0 = ((const uint32_t*)base)[idx4 * 2];
    uint32_t w1 = ((const uint32_t*)base)[idx4 * 2 + 1];
    uint32_t r = 0;
    r |= ((w0 & 0xFFFFu) != 0u) ? 0x00000001u : 0u;
    r |= ((w0 >> 16)     != 0u) ? 0x00000100u : 0u;
    r |= ((w1 & 0xFFFFu) != 0u) ? 0x00010000u : 0u;
    r |= ((w1 >> 16)     != 0u) ? 0x01000000u : 0u;
    return r;
  } else {
    uint4 w = ((const uint4*)base)[idx4];
    uint32_t r = 0;
    r |= (w.x != 0u) ? 0x00000001u : 0u;
    r |= (w.y != 0u) ? 0x00000100u : 0u;
    r |= (w.z != 0u) ? 0x00010000u : 0u;
    r |= (w.w != 0u) ? 0x01000000u : 0u;
    return r;
  }
}

__device__ __forceinline__ uint4 expand01(uint32_t v4) {
  uint4 r = { v4 & 1u, (v4 >> 8) & 1u, (v4 >> 16) & 1u, (v4 >> 24) & 1u };
  return r;
}

// ---- device-scope producer/consumer handshake (r3/r4-proven) ----
// producer: stores -> __syncthreads (per-wave vmcnt drain) -> thread0 bump
//           { __threadfence (cache-wide L2 writeback) ; relaxed agent add }
// consumer: thread0 { relaxed agent spin ; __threadfence } -> __syncthreads
__device__ __forceinline__ void wait_ge(uint32_t* p, uint32_t tgt) {
  while (__hip_atomic_load(p, __ATOMIC_RELAXED, __HIP_MEMORY_SCOPE_AGENT) < tgt)
    __builtin_amdgcn_s_sleep(2);
  __threadfence();
}
__device__ __forceinline__ void bump(uint32_t* p) {
  __threadfence();
  __hip_atomic_fetch_add(p, 1u, __ATOMIC_RELAXED, __HIP_MEMORY_SCOPE_AGENT);
}

// flag zeroing as a 5us kernel node instead of hipMemsetAsync (r3/r4 showed a
// stable ~292us total-minus-dispatch gap that appeared exactly when the memset
// entered the launch path — this tests and removes that suspect).
__global__ __launch_bounds__(256) void zero_kernel(uint32_t* __restrict__ f) {
  f[threadIdx.x] = 0;
}

// ---------------- mega-kernel: 1 scan block + 255 persistent workers --------
// r4 falsified CU-contention (exclusive CUs: 838->835). Remaining suspects for
// the scan's +300us vs its 533us floor: per-step vmcnt(0) drain of 16KB out-
// stores (syncthreads semantics) under a contended memory subsystem, and the
// 64 group handshakes. This round:
//  * BATCH-PACKED scan: h byte = 8 batch bits; in_orb is already packed, so the
//    SAME 12 gathers + AND compute all 8 batches in ONE block (bitwise ops act
//    per-batch-lane). Per-step store: 4KB packed row (1 word/thread) instead of
//    16KB int32 expand — 4x lighter drain; h-expansion moves to workers.
//  * persistent workers (256 blocks x 88KiB LDS = exactly 1/CU, all resident):
//    task queue detect -> ext-in -> ext-h -> inor -> expand. Queue order makes
//    it deadlock-free: scan depends only on tasks queued before any expander.
__global__ __launch_bounds__(1024) void mega_kernel(const void* __restrict__ z,
                                                    const void* __restrict__ h0,
                                                    const float* __restrict__ Ain,
                                                    const float* __restrict__ Ah,
                                                    uint32_t* __restrict__ modep,
                                                    uint32_t* __restrict__ idxin,
                                                    uint32_t* __restrict__ idxh,
                                                    uint32_t* __restrict__ inorb,
                                                    uint32_t* __restrict__ hseq,
                                                    uint32_t* __restrict__ flags,
                                                    uint32_t* __restrict__ out) {
  // 88 KiB forces 1 block/CU (256 blocks -> every CU, all resident immediately)
  __shared__ __align__(16) unsigned char smem[88 * 1024];
  unsigned char* sm0 = &smem[0];            // scan dbuf[0] / worker zp
  unsigned char* sm1 = &smem[4096];         // scan dbuf[1]
  int* scnt = (int*)&smem[8192];            // worker scratch (16 ints)
  __shared__ int tsk;
  const int n = threadIdx.x;

  if (blockIdx.x == 0) {
    // ================= batch-packed scan (exclusive CU) =================
    __builtin_amdgcn_s_setprio(1);
    if (n == 0) wait_ge(&flags[F_MODE], 1);
    __syncthreads();
    const int es = (int)modep[0];
    // packed h(-1): byte i = bit b of h0[b][i]
    uint32_t acc = 0;
    #pragma unroll
    for (int b = 0; b < B_; ++b) acc |= load4(h0, (long)b * 1024 + n, es) << b;
    ((uint32_t*)sm0)[n] = acc;
    if (n == 0) wait_ge(&flags[F_EXH], 256);   // idxh ready
    __syncthreads();
    uint32_t d[4][3];
    {
      const uint4* p = (const uint4*)(idxh + n * 12);
      uint4 q0 = p[0], q1 = p[1], q2 = p[2];
      d[0][0] = q0.x; d[0][1] = q0.y; d[0][2] = q0.z;
      d[1][0] = q0.w; d[1][1] = q1.x; d[1][2] = q1.y;
      d[2][0] = q1.z; d[2][1] = q1.w; d[2][2] = q2.x;
      d[3][0] = q2.y; d[3][1] = q2.z; d[3][2] = q2.w;
    }
    __syncthreads();
    int p = 0;
    for (int g = 0; g < NGRP; ++g) {
      if (n == 0) wait_ge(&flags[F_INOR + g], GRP);
      __syncthreads();
      uint32_t inw = inorb[(g * GRP) * 1024 + n];
      for (int tt = 0; tt < GRP; ++tt) {
        const int t = g * GRP + tt;
        uint32_t inw_next = (tt < GRP - 1) ? inorb[(t + 1) * 1024 + n] : 0u;
        const unsigned char* hc = p ? sm1 : sm0;
        unsigned char* hn = p ? sm0 : sm1;
        // each gathered byte carries 8 batch bits; OR/AND act per-batch-lane
        uint32_t v0 = (uint32_t)hc[d[0][0]] | hc[d[0][1]] | hc[d[0][2]];
        uint32_t v1 = (uint32_t)hc[d[1][0]] | hc[d[1][1]] | hc[d[1][2]];
        uint32_t v2 = (uint32_t)hc[d[2][0]] | hc[d[2][1]] | hc[d[2][2]];
        uint32_t v3 = (uint32_t)hc[d[3][0]] | hc[d[3][1]] | hc[d[3][2]];
        uint32_t o4 = (v0 | (v1 << 8) | (v2 << 16) | (v3 << 24)) & inw;
        ((uint32_t*)hn)[n] = o4;
        hseq[(size_t)t * 1024 + n] = o4;     // 4B/thread packed row (was 16B)
        __syncthreads();                      // also drains the hseq store
        inw = inw_next;
        p ^= 1;
      }
      if (n == 0) bump(&flags[F_SCAN + g]);  // rows g*GRP.. visible (fence in bump)
    }
    return;
  }

  // ================= persistent worker =================
  uint32_t* qctr = &flags[F_QCTR];
  for (;;) {
    __syncthreads();                          // protect tsk & smem reuse
    if (n == 0) tsk = (int)__hip_atomic_fetch_add(qctr, 1u, __ATOMIC_RELAXED,
                                                  __HIP_MEMORY_SCOPE_AGENT);
    __syncthreads();
    const int task = tsk;
    if (task >= TK_END) return;

    if (task == TK_DETECT) {
      // ---- encoding detection ----
      if (n == 0) { scnt[0] = 1; scnt[1] = 1; scnt[2] = 1; scnt[3] = 0; }
      __syncthreads();
      const uint32_t* zw = (const uint32_t*)z;
      int okB = 1, okH = 1, okW = 1, low = 0;
      #pragma unroll
      for (int k = 0; k < 4; ++k) {
        uint32_t w = zw[n + 1024 * k];
        if ((w & 0xFEFEFEFEu) != 0u) okB = 0;
        uint32_t lo = w & 0xFFFFu, hi = w >> 16;
        if (!((lo == 0u || lo == 0x3F80u) && (hi == 0u || hi == 0x3F80u))) okH = 0;
        if (!(w == 0u || w == 1u)) okW = 0;
        if (lo != 0u) low = 1;
      }
      if (!okB) atomicAnd(&scnt[0], 0);
      if (!okH) atomicAnd(&scnt[1], 0);
      if (!okW) atomicAnd(&scnt[2], 0);
      if (low)  atomicOr(&scnt[3], 1);
      __syncthreads();
      if (n == 0) {
        uint32_t mode;
        if (scnt[2])      mode = 4;
        else if (scnt[0]) mode = 1;
        else if (scnt[1]) mode = scnt[3] ? 2 : 4;
        else              mode = 1;
        modep[0] = mode;
        bump(&flags[F_MODE]);
      }
      continue;
    }

    if (task < TK_INOR0) {
      // ---- fan-in extraction, 16 rows ----
      const int isIn = (task < TK_EXTH0);
      const int eb = task - (isIn ? TK_EXTIN0 : TK_EXTH0);   // 0..255
      const int wave = n >> 6, lane = n & 63;
      const int row = eb * 16 + wave;
      const float* A = (isIn ? Ain : Ah) + (long)row * 4096;
      uint32_t* outp = (isIn ? idxin : idxh) + row * 3;
      if (lane == 0) scnt[wave] = 0;
      __syncthreads();
      const float4* A4 = (const float4*)A;
      #pragma unroll
      for (int it = 0; it < 16; ++it) {
        float4 v = A4[it * 64 + lane];
        int cbase = (it * 64 + lane) * 4;
        if (v.x != 0.0f) { int q = atomicAdd(&scnt[wave], 1); if (q < 3) outp[q] = cbase;     }
        if (v.y != 0.0f) { int q = atomicAdd(&scnt[wave], 1); if (q < 3) outp[q] = cbase + 1; }
        if (v.z != 0.0f) { int q = atomicAdd(&scnt[wave], 1); if (q < 3) outp[q] = cbase + 2; }
        if (v.w != 0.0f) { int q = atomicAdd(&scnt[wave], 1); if (q < 3) outp[q] = cbase + 3; }
      }
      __syncthreads();
      if (n == 0) bump(isIn ? &flags[F_EXIN] : &flags[F_EXH]);
      continue;
    }

    if (task < TK_EXP0) {
      // ---- in-OR + z-copy, t = task - TK_INOR0 ----
      const int t = task - TK_INOR0;
      if (n == 0) { wait_ge(&flags[F_MODE], 1); wait_ge(&flags[F_EXIN], 256); }
      __syncthreads();
      const int es = (int)modep[0];
      uint32_t acc = 0;
      #pragma unroll
      for (int b = 0; b < B_; ++b) {
        uint32_t v4 = load4(z, ((long)b * T_ + t) * 1024 + n, es);
        acc |= v4 << b;
        ((uint4*)(out + ((long)b * T_ + t) * 8192))[n] = expand01(v4);
      }
      ((uint32_t*)sm0)[n] = acc;
      __syncthreads();
      const unsigned char* zp = sm0;
      const uint4* ip = (const uint4*)(idxin + n * 12);
      uint4 q0 = ip[0], q1 = ip[1], q2 = ip[2];
      uint32_t r0 = (uint32_t)zp[q0.x] | zp[q0.y] | zp[q0.z];
      uint32_t r1 = (uint32_t)zp[q0.w] | zp[q1.x] | zp[q1.y];
      uint32_t r2 = (uint32_t)zp[q1.z] | zp[q1.w] | zp[q2.x];
      uint32_t r3 = (uint32_t)zp[q2.y] | zp[q2.z] | zp[q2.w];
      inorb[t * 1024 + n] = r0 | (r1 << 8) | (r2 << 16) | (r3 << 24);
      __syncthreads();
      if (n == 0) bump(&flags[F_INOR + (t >> 4)]);
      continue;
    }

    {
      // ---- h-half expansion, t = task - TK_EXP0 (chases the scan) ----
      const int t = task - TK_EXP0;
      if (n == 0) wait_ge(&flags[F_SCAN + (t >> 4)], 1);
      __syncthreads();
      const uint32_t w = hseq[(size_t)t * 1024 + n];
      #pragma unroll
      for (int b = 0; b < B_; ++b)
        ((uint4*)(out + ((long)b * T_ + t) * 8192 + 4096))[n] =
            expand01((w >> b) & 0x01010101u);
      continue;
    }
  }
}

// ---------------- launch ----------------
extern "C" void kernel_launch(void* const* d_in, const int* in_sizes, int n_in,
                              void* d_out, int out_size, void* d_ws, size_t ws_size,
                              hipStream_t stream) {
  const void*  z   = d_in[0];                 // bool (B,T,CIN) - int32 0/1 (detected)
  const void*  h0  = d_in[1];                 // bool (B,CH)
  const float* Ain = (const float*)d_in[2];   // (CH,CIN) f32
  const float* Ah  = (const float*)d_in[3];   // (CH,CH)  f32
  uint32_t* out = (uint32_t*)d_out;           // int32 0/1

  char* ws = (char*)d_ws;
  // ws layout (bytes):
  // [0]       mode (256 reserved)
  // [256]     idx_in 48K
  // [49408]   idx_h  48K
  // [98560]   in_orb 4MiB                      -> end 4292864
  // [4292864] flags 1K (256 u32: sync flags + task-queue counter)
  // [4293888] hseq  4MiB (packed h rows, u32[1024][1024])
  uint32_t* modep = (uint32_t*)(ws);
  uint32_t* idxin = (uint32_t*)(ws + 256);
  uint32_t* idxh  = (uint32_t*)(ws + 256 + 49152);
  uint32_t* inorb = (uint32_t*)(ws + 98560);
  uint32_t* flagp = (uint32_t*)(ws + 4292864);
  uint32_t* hseq  = (uint32_t*)(ws + 4293888);

  zero_kernel<<<1, 256, 0, stream>>>(flagp);
  mega_kernel<<<256, 1024, 0, stream>>>(z, h0, Ain, Ah, modep, idxin, idxh,
                                        inorb, hseq, flagp, out);
}

// Round 6
// 1173.254 us; speedup vs baseline: 1.0908x; 1.0908x over previous
//
#include <hip/hip_runtime.h>
#include <stdint.h>

#define B_   8
#define T_   1024
#define CIN_ 4096
#define CH_  4096
#define GRP  16               // scan group size (steps per stage/flush)
#define NGRP (T_ / GRP)
#define NCOPY 512             // copy blocks in K3 (blocks 8..8+NCOPY-1)

// ---------------- helpers ----------------

__device__ __forceinline__ uint32_t bytes_nonzero01(uint32_t w) {
  uint32_t t = (w & 0x7F7F7F7Fu) + 0x7F7F7F7Fu;
  t = (t | w) & 0x80808080u;
  return t >> 7;
}

// load 4 consecutive boolean elements (elements idx4*4..+3) from a buffer with
// element size es (1,2,4 bytes); return packed 0/1 bytes.
__device__ __forceinline__ uint32_t load4(const void* base, long idx4, int es) {
  if (es == 1) {
    uint32_t w = ((const uint32_t*)base)[idx4];
    return bytes_nonzero01(w);
  } else if (es == 2) {
    uint32_t w0 = ((const uint32_t*)base)[idx4 * 2];
    uint32_t w1 = ((const uint32_t*)base)[idx4 * 2 + 1];
    uint32_t r = 0;
    r |= ((w0 & 0xFFFFu) != 0u) ? 0x00000001u : 0u;
    r |= ((w0 >> 16)     != 0u) ? 0x00000100u : 0u;
    r |= ((w1 & 0xFFFFu) != 0u) ? 0x00010000u : 0u;
    r |= ((w1 >> 16)     != 0u) ? 0x01000000u : 0u;
    return r;
  } else {
    uint4 w = ((const uint4*)base)[idx4];
    uint32_t r = 0;
    r |= (w.x != 0u) ? 0x00000001u : 0u;
    r |= (w.y != 0u) ? 0x00000100u : 0u;
    r |= (w.z != 0u) ? 0x00010000u : 0u;
    r |= (w.w != 0u) ? 0x01000000u : 0u;
    return r;
  }
}

__device__ __forceinline__ uint4 expand01(uint32_t v4) {
  uint4 r = { v4 & 1u, (v4 >> 8) & 1u, (v4 >> 16) & 1u, (v4 >> 24) & 1u };
  return r;
}

// ---------------- kernel 1: fan-in index extraction + encoding detect --------
// r0-proven. Blocks 0..2047: one wave per row (0..4095 = A_input, 4096..8191 =
// A_hidden). Block 2048: encoding detection.
__global__ __launch_bounds__(256) void extract_kernel(const float* __restrict__ Ain,
                                                      const float* __restrict__ Ah,
                                                      uint32_t* __restrict__ idxin,
                                                      uint32_t* __restrict__ idxh,
                                                      const uint32_t* __restrict__ z,
                                                      uint32_t* __restrict__ modep) {
  if (blockIdx.x == 2048) {
    __shared__ int sB, sH, sW, sL;
    const int n = threadIdx.x;
    if (n == 0) { sB = 1; sH = 1; sW = 1; sL = 0; }
    __syncthreads();
    int okB = 1, okH = 1, okW = 1, low = 0;
    for (int k = 0; k < 16; ++k) {
      uint32_t w = z[n + 256 * k];
      if ((w & 0xFEFEFEFEu) != 0u) okB = 0;
      uint32_t lo = w & 0xFFFFu, hi = w >> 16;
      if (!((lo == 0u || lo == 0x3F80u) && (hi == 0u || hi == 0x3F80u))) okH = 0;
      if (!(w == 0u || w == 1u)) okW = 0;
      if (lo != 0u) low = 1;
    }
    if (!okB) atomicAnd(&sB, 0);
    if (!okH) atomicAnd(&sH, 0);
    if (!okW) atomicAnd(&sW, 0);
    if (low)  atomicOr(&sL, 1);
    __syncthreads();
    if (n == 0) {
      uint32_t mode;
      if (sW)      mode = 4;              // int32 0/1
      else if (sB) mode = 1;              // uint8 bool
      else if (sH) mode = sL ? 2 : 4;     // bf16 : float32
      else         mode = 1;
      modep[0] = mode;
    }
    return;
  }
  const int wave = threadIdx.x >> 6;
  const int lane = threadIdx.x & 63;
  const int row  = blockIdx.x * 4 + wave;   // 0..8191
  const float* A;
  uint32_t* outp;
  if (row < 4096) { A = Ain + (long)row * 4096;          outp = idxin + row * 3; }
  else            { A = Ah  + (long)(row - 4096) * 4096; outp = idxh + (row - 4096) * 3; }
  __shared__ int cnt[4];
  if (lane == 0) cnt[wave] = 0;
  __syncthreads();
  const float4* A4 = (const float4*)A;
  #pragma unroll
  for (int it = 0; it < 16; ++it) {
    float4 v = A4[it * 64 + lane];
    int cbase = (it * 64 + lane) * 4;
    if (v.x != 0.0f) { int q = atomicAdd(&cnt[wave], 1); if (q < 3) outp[q] = cbase;     }
    if (v.y != 0.0f) { int q = atomicAdd(&cnt[wave], 1); if (q < 3) outp[q] = cbase + 1; }
    if (v.z != 0.0f) { int q = atomicAdd(&cnt[wave], 1); if (q < 3) outp[q] = cbase + 2; }
    if (v.w != 0.0f) { int q = atomicAdd(&cnt[wave], 1); if (q < 3) outp[q] = cbase + 3; }
  }
}

// ---------------- kernel 2: in-OR precompute ONLY (no z-copy) ----------------
// r0's inor minus the 134MB out z-half writes (those move to K3's copy blocks,
// overlapped with the scan). Reads z 134MB, writes inorb 4MB.
__global__ __launch_bounds__(1024) void inor_kernel(const void* __restrict__ z,
                                                    const uint32_t* __restrict__ idxin,
                                                    const uint32_t* __restrict__ modep,
                                                    uint32_t* __restrict__ in_orb) {
  const int t = blockIdx.x;
  const int n = threadIdx.x;
  const int es = (int)modep[0];
  __shared__ __align__(16) unsigned char zp[4096];   // batch-packed z row
  uint32_t acc = 0;
  #pragma unroll
  for (int b = 0; b < B_; ++b)
    acc |= load4(z, ((long)b * T_ + t) * 1024 + n, es) << b;
  ((uint32_t*)zp)[n] = acc;
  __syncthreads();
  const uint4* ip = (const uint4*)(idxin + n * 12);
  uint4 q0 = ip[0], q1 = ip[1], q2 = ip[2];
  uint32_t r0 = (uint32_t)zp[q0.x] | zp[q0.y] | zp[q0.z];
  uint32_t r1 = (uint32_t)zp[q0.w] | zp[q1.x] | zp[q1.y];
  uint32_t r2 = (uint32_t)zp[q1.z] | zp[q1.w] | zp[q2.x];
  uint32_t r3 = (uint32_t)zp[q2.y] | zp[q2.z] | zp[q2.w];
  in_orb[t * 1024 + n] = r0 | (r1 << 8) | (r2 << 16) | (r3 << 24);
}

// ---------------- kernel 3: scan (contention-immune) + independent z-copy ----
// NO inter-block sync of any kind (r3-r5 lesson: flags/spins poison everything).
// Blocks 0..7: r0-proven per-batch scan, hardened against the concurrent copy
//   traffic: per 16-step group, (a) stage 16 inorb rows -> LDS (64KB), (b) run
//   16 steps touching ONLY LDS (per-step __syncthreads' vmcnt(0) is a no-op:
//   nothing in flight — the measured r3/r4/r5 +50%/step contention tax came
//   from per-step store/load drains), (c) accumulate the 16 output rows in
//   registers (oacc[16], static-indexed) and flush 256B/thread once per group.
// Blocks 8..8+NCOPY-1: grid-stride z -> out z-half copy (134MB r + 134MB w),
//   fully independent, hidden under the 533us scan chain. Zero DS ops, so it
//   cannot touch the scan's bound pipe even when co-resident.
__global__ __launch_bounds__(1024) void scan_copy_kernel(const uint32_t* __restrict__ in_orb,
                                                         const uint32_t* __restrict__ idxh,
                                                         const void* __restrict__ h0,
                                                         const void* __restrict__ z,
                                                         const uint32_t* __restrict__ modep,
                                                         uint32_t* __restrict__ out) {
  const int n = threadIdx.x;
  const int es = (int)modep[0];

  if (blockIdx.x >= 8) {
    // ================= independent z-copy (no LDS, no sync) =================
    const long total4 = (long)B_ * T_ * 1024;          // uint4-granular elements/4
    const long stride = (long)NCOPY * 1024;
    uint4* out4 = (uint4*)out;
    for (long i4 = (long)(blockIdx.x - 8) * 1024 + n; i4 < total4; i4 += stride) {
      uint32_t v = load4(z, i4, es);
      long row = i4 >> 10, c4 = i4 & 1023;             // (b*T+t), col/4
      out4[row * 2048 + c4] = expand01(v);
    }
    return;
  }

  // ================= scan block (batch b = blockIdx.x) =================
  __builtin_amdgcn_s_setprio(1);
  // 88KiB: 1 block/CU guaranteed (2x88 > 160) -> exclusive DS pipe
  __shared__ __align__(16) unsigned char smem[88 * 1024];
  unsigned char* hb0 = &smem[0];                       // h dbuf[0]
  unsigned char* hb1 = &smem[4096];                    // h dbuf[1]
  uint32_t* stg = (uint32_t*)&smem[8192];              // staged inorb, u32[16][1024]
  const int b = blockIdx.x;

  uint32_t d[4][3];
  {
    const uint4* p = (const uint4*)(idxh + n * 12);
    uint4 q0 = p[0], q1 = p[1], q2 = p[2];
    d[0][0] = q0.x; d[0][1] = q0.y; d[0][2] = q0.z;
    d[1][0] = q0.w; d[1][1] = q1.x; d[1][2] = q1.y;
    d[2][0] = q1.z; d[2][1] = q1.w; d[2][2] = q2.x;
    d[3][0] = q2.y; d[3][1] = q2.z; d[3][2] = q2.w;
  }
  ((uint32_t*)hb0)[n] = load4(h0, (long)b * 1024 + n, es);
  uint32_t* outh = out + (long)b * T_ * 8192 + 4096;

  for (int g = 0; g < NGRP; ++g) {
    // ---- stage 16 inorb rows (64KB) into LDS: 4 x uint4 per thread ----
    {
      const uint4* src = (const uint4*)(in_orb + g * (GRP * 1024));
      uint4 s0 = src[n], s1 = src[n + 1024], s2 = src[n + 2048], s3 = src[n + 3072];
      uint4* dst = (uint4*)stg;
      dst[n] = s0; dst[n + 1024] = s1; dst[n + 2048] = s2; dst[n + 3072] = s3;
    }
    __syncthreads();   // drains staging (and last group's flush stores, aged ~1 latency)

    uint32_t oacc[GRP];
    #pragma unroll
    for (int tt = 0; tt < GRP; ++tt) {
      const unsigned char* hc = (tt & 1) ? hb1 : hb0;
      unsigned char* hn = (tt & 1) ? hb0 : hb1;
      uint32_t inw = stg[tt * 1024 + n];
      uint32_t mask = (inw >> b) & 0x01010101u;
      uint32_t o4 = 0;
      if (mask) {
        if (mask & 0x00000001u) { uint32_t v = (uint32_t)hc[d[0][0]] | hc[d[0][1]] | hc[d[0][2]]; o4 |= v; }
        if (mask & 0x00000100u) { uint32_t v = (uint32_t)hc[d[1][0]] | hc[d[1][1]] | hc[d[1][2]]; o4 |= v << 8; }
        if (mask & 0x00010000u) { uint32_t v = (uint32_t)hc[d[2][0]] | hc[d[2][1]] | hc[d[2][2]]; o4 |= v << 16; }
        if (mask & 0x01000000u) { uint32_t v = (uint32_t)hc[d[3][0]] | hc[d[3][1]] | hc[d[3][2]]; o4 |= v << 24; }
      }
      ((uint32_t*)hn)[n] = o4;
      oacc[tt] = o4;
      __syncthreads();   // LDS-only step: vmcnt already 0 -> barrier is cheap
    }

    // ---- flush 16 output rows (fire-and-forget; drained at next stage sync) ----
    #pragma unroll
    for (int tt = 0; tt < GRP; ++tt)
      ((uint4*)(outh + (long)(g * GRP + tt) * 8192))[n] = expand01(oacc[tt]);
  }
}

// ---------------- launch ----------------
extern "C" void kernel_launch(void* const* d_in, const int* in_sizes, int n_in,
                              void* d_out, int out_size, void* d_ws, size_t ws_size,
                              hipStream_t stream) {
  const void*  z   = d_in[0];                 // bool (B,T,CIN) - int32 0/1 (detected)
  const void*  h0  = d_in[1];                 // bool (B,CH)
  const float* Ain = (const float*)d_in[2];   // (CH,CIN) f32
  const float* Ah  = (const float*)d_in[3];   // (CH,CH)  f32
  uint32_t* out = (uint32_t*)d_out;           // int32 0/1

  char* ws = (char*)d_ws;
  // ws layout (bytes): [0] mode (256 res) | [256] idx_in 48K | [49408] idx_h 48K |
  //                    [98560] in_orb 4MiB
  uint32_t* modep = (uint32_t*)(ws);
  uint32_t* idxin = (uint32_t*)(ws + 256);
  uint32_t* idxh  = (uint32_t*)(ws + 256 + 49152);
  uint32_t* inorb = (uint32_t*)(ws + 98560);

  extract_kernel  <<<2049, 256,  0, stream>>>(Ain, Ah, idxin, idxh,
                                              (const uint32_t*)z, modep);
  inor_kernel     <<<T_,   1024, 0, stream>>>(z, idxin, modep, inorb);
  scan_copy_kernel<<<8 + NCOPY, 1024, 0, stream>>>(inorb, idxh, h0, z, modep, out);
}

// Round 7
// 1090.837 us; speedup vs baseline: 1.1732x; 1.0756x over previous
//
#include <hip/hip_runtime.h>
#include <stdint.h>

#define B_   8
#define T_   1024
#define CIN_ 4096
#define CH_  4096
#define GRP  16               // scan steps per flag group
#define NGRP (T_ / GRP)

// flags: [8+g] = inor completion counter for group g (target GRP)
#define F_INOR 8

// ---------------- helpers ----------------

__device__ __forceinline__ uint32_t bytes_nonzero01(uint32_t w) {
  uint32_t t = (w & 0x7F7F7F7Fu) + 0x7F7F7F7Fu;
  t = (t | w) & 0x80808080u;
  return t >> 7;
}

// load 4 consecutive boolean elements (elements idx4*4..+3) from a buffer with
// element size es (1,2,4 bytes); return packed 0/1 bytes.
__device__ __forceinline__ uint32_t load4(const void* base, long idx4, int es) {
  if (es == 1) {
    uint32_t w = ((const uint32_t*)base)[idx4];
    return bytes_nonzero01(w);
  } else if (es == 2) {
    uint32_t w0 = ((const uint32_t*)base)[idx4 * 2];
    uint32_t w1 = ((const uint32_t*)base)[idx4 * 2 + 1];
    uint32_t r = 0;
    r |= ((w0 & 0xFFFFu) != 0u) ? 0x00000001u : 0u;
    r |= ((w0 >> 16)     != 0u) ? 0x00000100u : 0u;
    r |= ((w1 & 0xFFFFu) != 0u) ? 0x00010000u : 0u;
    r |= ((w1 >> 16)     != 0u) ? 0x01000000u : 0u;
    return r;
  } else {
    uint4 w = ((const uint4*)base)[idx4];
    uint32_t r = 0;
    r |= (w.x != 0u) ? 0x00000001u : 0u;
    r |= (w.y != 0u) ? 0x00000100u : 0u;
    r |= (w.z != 0u) ? 0x00010000u : 0u;
    r |= (w.w != 0u) ? 0x01000000u : 0u;
    return r;
  }
}

__device__ __forceinline__ uint4 expand01(uint32_t v4) {
  uint4 r = { v4 & 1u, (v4 >> 8) & 1u, (v4 >> 16) & 1u, (v4 >> 24) & 1u };
  return r;
}

// ---- device-scope producer/consumer handshake (r3..r6-proven, verbatim) ----
__device__ __forceinline__ void wait_ge(uint32_t* p, uint32_t tgt) {
  while (__hip_atomic_load(p, __ATOMIC_RELAXED, __HIP_MEMORY_SCOPE_AGENT) < tgt)
    __builtin_amdgcn_s_sleep(2);
  __threadfence();
}
__device__ __forceinline__ void bump(uint32_t* p) {
  __threadfence();
  __hip_atomic_fetch_add(p, 1u, __ATOMIC_RELAXED, __HIP_MEMORY_SCOPE_AGENT);
}

// ---------------- kernel 1: extract + detect(+flag-zero) + z-copy -----------
// bid 0..2047  : fan-in extraction, 4 rows/block (r0-proven)
// bid 2048     : encoding detect -> modep; zero the K2 flags
// bid 2049..3072: z -> out z-half copy (no deps; local es detect from z[0..16K);
//                134MB r + 134MB w on CUs extract doesn't use — K1 ~= copy time.
__global__ __launch_bounds__(256) void prep_kernel(const float* __restrict__ Ain,
                                                   const float* __restrict__ Ah,
                                                   uint32_t* __restrict__ idxin,
                                                   uint32_t* __restrict__ idxh,
                                                   const void* __restrict__ z,
                                                   uint32_t* __restrict__ modep,
                                                   uint32_t* __restrict__ flags,
                                                   uint32_t* __restrict__ out) {
  __shared__ int cnt[4];
  const int n = threadIdx.x;
  const uint32_t* zw = (const uint32_t*)z;

  if (blockIdx.x == 2048 || blockIdx.x > 2048) {
    // ---- shared detect logic (block 2048 publishes; copy blocks use locally) ----
    if (n == 0) { cnt[0] = 1; cnt[1] = 1; cnt[2] = 1; cnt[3] = 0; }
    __syncthreads();
    int okB = 1, okH = 1, okW = 1, low = 0;
    for (int k = 0; k < 16; ++k) {
      uint32_t w = zw[n + 256 * k];
      if ((w & 0xFEFEFEFEu) != 0u) okB = 0;
      uint32_t lo = w & 0xFFFFu, hi = w >> 16;
      if (!((lo == 0u || lo == 0x3F80u) && (hi == 0u || hi == 0x3F80u))) okH = 0;
      if (!(w == 0u || w == 1u)) okW = 0;
      if (lo != 0u) low = 1;
    }
    if (!okB) atomicAnd(&cnt[0], 0);
    if (!okH) atomicAnd(&cnt[1], 0);
    if (!okW) atomicAnd(&cnt[2], 0);
    if (low)  atomicOr(&cnt[3], 1);
    __syncthreads();
    uint32_t mode;
    if (cnt[2])      mode = 4;                // int32 0/1
    else if (cnt[0]) mode = 1;                // uint8 bool
    else if (cnt[1]) mode = cnt[3] ? 2 : 4;   // bf16 : float32
    else             mode = 1;

    if (blockIdx.x == 2048) {
      if (n == 0) modep[0] = mode;
      if (n < 128) flags[n] = 0;              // K2 flags (stream-ordered visible)
      return;
    }
    // ---- z-copy: grid-stride, 1024 blocks x 256 thr x 32 uint4 ----
    const int es = (int)mode;
    uint4* out4 = (uint4*)out;
    long i4 = (long)(blockIdx.x - 2049) * 256 + n;
    #pragma unroll 4
    for (int k = 0; k < 32; ++k, i4 += 262144) {
      uint32_t v = load4(z, i4, es);
      long row = i4 >> 10, c4 = i4 & 1023;    // (b*T+t), col/4
      out4[row * 2048 + c4] = expand01(v);
    }
    return;
  }

  // ---- extraction: 4 rows/block, one wave per row (r0-proven) ----
  const int wave = n >> 6;
  const int lane = n & 63;
  const int row  = blockIdx.x * 4 + wave;     // 0..8191
  const float* A;
  uint32_t* outp;
  if (row < 4096) { A = Ain + (long)row * 4096;          outp = idxin + row * 3; }
  else            { A = Ah  + (long)(row - 4096) * 4096; outp = idxh + (row - 4096) * 3; }
  if (lane == 0) cnt[wave] = 0;
  __syncthreads();
  const float4* A4 = (const float4*)A;
  #pragma unroll
  for (int it = 0; it < 16; ++it) {
    float4 v = A4[it * 64 + lane];
    int cbase = (it * 64 + lane) * 4;
    if (v.x != 0.0f) { int q = atomicAdd(&cnt[wave], 1); if (q < 3) outp[q] = cbase;     }
    if (v.y != 0.0f) { int q = atomicAdd(&cnt[wave], 1); if (q < 3) outp[q] = cbase + 1; }
    if (v.z != 0.0f) { int q = atomicAdd(&cnt[wave], 1); if (q < 3) outp[q] = cbase + 2; }
    if (v.w != 0.0f) { int q = atomicAdd(&cnt[wave], 1); if (q < 3) outp[q] = cbase + 3; }
  }
}

// ---------------- kernel 2: scan (VMEM-silent inner loop) + inor producers ---
// bid 0..7   : scan, batch b = bid. 88KiB LDS -> exclusive CU. Per 16-step
//   group: flag-wait (thread0) -> barrier -> inorb group into REGISTERS cur[16]
//   -> 16 DS-only steps (192 gathers + 16 writes = r0's 208 ops; zero VMEM in
//   flight, so each step's implied vmcnt(0) is free — the r3-r5 poison) ->
//   batched flush of oacc[16] (drained once at next group's barrier).
// bid 8..1031: inor producer for t = bid-8 (r6 body) -> bump flags[8+t/16].
//   Producer pace ~5.5us/group < scan ~9us/group -> scan never starves.
// Deadlock-free: producers never wait on scan; scan blocks dispatch first.
__global__ __launch_bounds__(1024) void scan_inor_kernel(const void* __restrict__ z,
                                                         const void* __restrict__ h0,
                                                         const uint32_t* __restrict__ modep,
                                                         const uint32_t* __restrict__ idxin,
                                                         const uint32_t* __restrict__ idxh,
                                                         uint32_t* __restrict__ inorb,
                                                         uint32_t* __restrict__ flags,
                                                         uint32_t* __restrict__ out) {
  __shared__ __align__(16) unsigned char smem[88 * 1024];  // 1 block/CU
  unsigned char* hb0 = &smem[0];           // scan h dbuf[0] / inor zp
  unsigned char* hb1 = &smem[4096];        // scan h dbuf[1]
  const int n = threadIdx.x;
  const int es = (int)modep[0];

  if (blockIdx.x >= 8) {
    // ================= inor producer (t = bid - 8) =================
    const int t = (int)blockIdx.x - 8;
    uint32_t acc = 0;
    #pragma unroll
    for (int b = 0; b < B_; ++b)
      acc |= load4(z, ((long)b * T_ + t) * 1024 + n, es) << b;
    ((uint32_t*)hb0)[n] = acc;
    __syncthreads();
    const unsigned char* zp = hb0;
    const uint4* ip = (const uint4*)(idxin + n * 12);
    uint4 q0 = ip[0], q1 = ip[1], q2 = ip[2];
    uint32_t r0 = (uint32_t)zp[q0.x] | zp[q0.y] | zp[q0.z];
    uint32_t r1 = (uint32_t)zp[q0.w] | zp[q1.x] | zp[q1.y];
    uint32_t r2 = (uint32_t)zp[q1.z] | zp[q1.w] | zp[q2.x];
    uint32_t r3 = (uint32_t)zp[q2.y] | zp[q2.z] | zp[q2.w];
    inorb[t * 1024 + n] = r0 | (r1 << 8) | (r2 << 16) | (r3 << 24);
    __syncthreads();                         // all stores issued+drained per wave
    if (n == 0) bump(&flags[F_INOR + (t >> 4)]);
    return;
  }

  // ================= scan block (batch b = blockIdx.x) =================
  __builtin_amdgcn_s_setprio(1);
  const int b = (int)blockIdx.x;

  uint32_t d[4][3];
  {
    const uint4* p = (const uint4*)(idxh + n * 12);
    uint4 q0 = p[0], q1 = p[1], q2 = p[2];
    d[0][0] = q0.x; d[0][1] = q0.y; d[0][2] = q0.z;
    d[1][0] = q0.w; d[1][1] = q1.x; d[1][2] = q1.y;
    d[2][0] = q1.z; d[2][1] = q1.w; d[2][2] = q2.x;
    d[3][0] = q2.y; d[3][1] = q2.z; d[3][2] = q2.w;
  }
  ((uint32_t*)hb0)[n] = load4(h0, (long)b * 1024 + n, es);
  uint32_t* outh = out + (long)b * T_ * 8192 + 4096;

  // prologue: group 0 into registers
  if (n == 0) wait_ge(&flags[F_INOR + 0], GRP);
  __syncthreads();                            // h0 visible + flag broadcast
  uint32_t cur[GRP], nxt[GRP], oacc[GRP];
  #pragma unroll
  for (int i = 0; i < GRP; ++i) cur[i] = inorb[i * 1024 + n];

  for (int g = 0; g < NGRP; ++g) {
    // prefetch next group's inorb rows into nxt (latency hidden by 16 steps)
    if (g + 1 < NGRP) {
      if (n == 0) wait_ge(&flags[F_INOR + g + 1], GRP);
      __syncthreads();
      #pragma unroll
      for (int i = 0; i < GRP; ++i) nxt[i] = inorb[((g + 1) * GRP + i) * 1024 + n];
    }
    // ---- 16 DS-only steps (no VMEM at step barriers) ----
    #pragma unroll
    for (int tt = 0; tt < GRP; ++tt) {
      const unsigned char* hc = (tt & 1) ? hb1 : hb0;
      unsigned char* hn = (tt & 1) ? hb0 : hb1;
      uint32_t mask = (cur[tt] >> b) & 0x01010101u;
      uint32_t o4 = 0;
      if (mask) {
        if (mask & 0x00000001u) { uint32_t v = (uint32_t)hc[d[0][0]] | hc[d[0][1]] | hc[d[0][2]]; o4 |= v; }
        if (mask & 0x00000100u) { uint32_t v = (uint32_t)hc[d[1][0]] | hc[d[1][1]] | hc[d[1][2]]; o4 |= v << 8; }
        if (mask & 0x00010000u) { uint32_t v = (uint32_t)hc[d[2][0]] | hc[d[2][1]] | hc[d[2][2]]; o4 |= v << 16; }
        if (mask & 0x01000000u) { uint32_t v = (uint32_t)hc[d[3][0]] | hc[d[3][1]] | hc[d[3][2]]; o4 |= v << 24; }
      }
      ((uint32_t*)hn)[n] = o4;
      oacc[tt] = o4;
      __syncthreads();
    }
    // ---- batched flush (fire-and-forget; drained at next group's barrier) ----
    #pragma unroll
    for (int tt = 0; tt < GRP; ++tt)
      ((uint4*)(outh + (long)(g * GRP + tt) * 8192))[n] = expand01(oacc[tt]);
    #pragma unroll
    for (int i = 0; i < GRP; ++i) cur[i] = nxt[i];
  }
}

// ---------------- launch ----------------
extern "C" void kernel_launch(void* const* d_in, const int* in_sizes, int n_in,
                              void* d_out, int out_size, void* d_ws, size_t ws_size,
                              hipStream_t stream) {
  const void*  z   = d_in[0];                 // bool (B,T,CIN) - int32 0/1 (detected)
  const void*  h0  = d_in[1];                 // bool (B,CH)
  const float* Ain = (const float*)d_in[2];   // (CH,CIN) f32
  const float* Ah  = (const float*)d_in[3];   // (CH,CH)  f32
  uint32_t* out = (uint32_t*)d_out;           // int32 0/1

  char* ws = (char*)d_ws;
  // ws layout (bytes): [0] mode (256 res) | [256] idx_in 48K | [49408] idx_h 48K |
  //                    [98560] in_orb 4MiB | [4292864] flags 512B
  uint32_t* modep = (uint32_t*)(ws);
  uint32_t* idxin = (uint32_t*)(ws + 256);
  uint32_t* idxh  = (uint32_t*)(ws + 256 + 49152);
  uint32_t* inorb = (uint32_t*)(ws + 98560);
  uint32_t* flagp = (uint32_t*)(ws + 4292864);

  prep_kernel     <<<3073, 256,  0, stream>>>(Ain, Ah, idxin, idxh, z,
                                              modep, flagp, out);
  scan_inor_kernel<<<8 + T_, 1024, 0, stream>>>(z, h0, modep, idxin, idxh,
                                                inorb, flagp, out);
}

// Round 9
// 1004.071 us; speedup vs baseline: 1.2746x; 1.0864x over previous
//
#include <hip/hip_runtime.h>
#include <stdint.h>

#define B_   8
#define T_   1024
#define CIN_ 4096
#define CH_  4096

// ---------------- helpers ----------------

// per-byte nonzero -> 0x01, packed
__device__ __forceinline__ uint32_t bytes_nonzero01(uint32_t w) {
  uint32_t t = (w & 0x7F7F7F7Fu) + 0x7F7F7F7Fu;
  t = (t | w) & 0x80808080u;
  return t >> 7;
}

// load 4 consecutive boolean elements (elements idx4*4..+3) from a buffer with
// element size es (1,2,4 bytes); return packed 0/1 bytes.
__device__ __forceinline__ uint32_t load4(const void* base, long idx4, int es) {
  if (es == 1) {
    uint32_t w = ((const uint32_t*)base)[idx4];
    return bytes_nonzero01(w);
  } else if (es == 2) {
    uint32_t w0 = ((const uint32_t*)base)[idx4 * 2];
    uint32_t w1 = ((const uint32_t*)base)[idx4 * 2 + 1];
    uint32_t r = 0;
    r |= ((w0 & 0xFFFFu) != 0u) ? 0x00000001u : 0u;
    r |= ((w0 >> 16)     != 0u) ? 0x00000100u : 0u;
    r |= ((w1 & 0xFFFFu) != 0u) ? 0x00010000u : 0u;
    r |= ((w1 >> 16)     != 0u) ? 0x01000000u : 0u;
    return r;
  } else {
    uint4 w = ((const uint4*)base)[idx4];
    uint32_t r = 0;
    r |= (w.x != 0u) ? 0x00000001u : 0u;
    r |= (w.y != 0u) ? 0x00000100u : 0u;
    r |= (w.z != 0u) ? 0x00010000u : 0u;
    r |= (w.w != 0u) ? 0x01000000u : 0u;
    return r;
  }
}

// expand 4 packed 0/1 bytes into 4 int32 0/1
__device__ __forceinline__ uint4 expand01(uint32_t v4) {
  uint4 r = { v4 & 1u, (v4 >> 8) & 1u, (v4 >> 16) & 1u, (v4 >> 24) & 1u };
  return r;
}

// ---------------- kernel 1: fan-in extraction + encoding detect (r0-proven) --
__global__ __launch_bounds__(256) void extract_kernel(const float* __restrict__ Ain,
                                                      const float* __restrict__ Ah,
                                                      uint32_t* __restrict__ idxin,
                                                      uint32_t* __restrict__ idxh,
                                                      const uint32_t* __restrict__ z,
                                                      uint32_t* __restrict__ modep) {
  if (blockIdx.x == 2048) {
    __shared__ int sB, sH, sW, sL;
    const int n = threadIdx.x;
    if (n == 0) { sB = 1; sH = 1; sW = 1; sL = 0; }
    __syncthreads();
    int okB = 1, okH = 1, okW = 1, low = 0;
    for (int k = 0; k < 16; ++k) {
      uint32_t w = z[n + 256 * k];
      if ((w & 0xFEFEFEFEu) != 0u) okB = 0;
      uint32_t lo = w & 0xFFFFu, hi = w >> 16;
      if (!((lo == 0u || lo == 0x3F80u) && (hi == 0u || hi == 0x3F80u))) okH = 0;
      if (!(w == 0u || w == 1u)) okW = 0;
      if (lo != 0u) low = 1;
    }
    if (!okB) atomicAnd(&sB, 0);
    if (!okH) atomicAnd(&sH, 0);
    if (!okW) atomicAnd(&sW, 0);
    if (low)  atomicOr(&sL, 1);
    __syncthreads();
    if (n == 0) {
      uint32_t mode;
      if (sW)      mode = 4;              // int32 0/1
      else if (sB) mode = 1;              // uint8 bool
      else if (sH) mode = sL ? 2 : 4;     // bf16 : float32
      else         mode = 1;
      modep[0] = mode;
    }
    return;
  }
  const int wave = threadIdx.x >> 6;
  const int lane = threadIdx.x & 63;
  const int row  = blockIdx.x * 4 + wave;   // 0..8191
  const float* A;
  uint32_t* outp;
  if (row < 4096) { A = Ain + (long)row * 4096;          outp = idxin + row * 3; }
  else            { A = Ah  + (long)(row - 4096) * 4096; outp = idxh + (row - 4096) * 3; }
  __shared__ int cnt[4];
  if (lane == 0) cnt[wave] = 0;
  __syncthreads();
  const float4* A4 = (const float4*)A;
  #pragma unroll
  for (int it = 0; it < 16; ++it) {
    float4 v = A4[it * 64 + lane];
    int cbase = (it * 64 + lane) * 4;
    if (v.x != 0.0f) { int q = atomicAdd(&cnt[wave], 1); if (q < 3) outp[q] = cbase;     }
    if (v.y != 0.0f) { int q = atomicAdd(&cnt[wave], 1); if (q < 3) outp[q] = cbase + 1; }
    if (v.z != 0.0f) { int q = atomicAdd(&cnt[wave], 1); if (q < 3) outp[q] = cbase + 2; }
    if (v.w != 0.0f) { int q = atomicAdd(&cnt[wave], 1); if (q < 3) outp[q] = cbase + 3; }
  }
}

// ---------------- kernel 2: in-OR + z-copy (r0) + FAST gather scheduler ------
// Blocks 0..1023: r0-proven inor body (z read once; writes z-half of out + inorb).
// Block 1024: conflict-aware gather schedule for the scan (r1's proven FORMAT,
//   recomputed fast). r1's lane-serial greedy was ~460us (64 sequential lane
//   phases x 12 dependent LDS reads); this entry-major version runs all lanes
//   in parallel (2 half-phases bound staleness to 32 lanes; intra-wave program
//   order makes LDS updates visible without barriers; waves independent).
//   ~3-5us — hidden under the ~84us inor blocks. Any per-lane slot PERMUTATION
//   is bit-correct (OR is commutative); quality only affects conflict cycles.
__global__ __launch_bounds__(1024) void inor_sched_kernel(const void* __restrict__ z,
                                                          const uint32_t* __restrict__ idxin,
                                                          const uint32_t* __restrict__ idxh,
                                                          const uint32_t* __restrict__ modep,
                                                          uint32_t* __restrict__ in_orb,
                                                          uint32_t* __restrict__ sched,
                                                          uint32_t* __restrict__ out) {
  __shared__ __align__(16) unsigned char smem[16 * 12 * 32 * 4];  // 24KB
  const int n = threadIdx.x;

  if (blockIdx.x == T_) {
    // ================= scheduler =================
    const int wv = n >> 6, ln = n & 63;
    uint32_t (*cnt)[12][32] = (uint32_t(*)[12][32])smem;
    // my 12 entries: entry e -> source d[e], dest sub-neuron j = e/3
    const uint4* p = (const uint4*)(idxh + n * 12);
    uint4 q0 = p[0], q1 = p[1], q2 = p[2];
    uint32_t d[12] = { q0.x, q0.y, q0.z,  q0.w, q1.x, q1.y,
                       q1.z, q1.w, q2.x,  q2.y, q2.z, q2.w };
    // zero counters (all waves zero all slices; one barrier)
    #pragma unroll
    for (int i = 0; i < 6; ++i) ((uint32_t*)smem)[n + i * 1024] = 0;
    __syncthreads();
    // entry-major parallel greedy: 12 entries x 2 lane-half phases
    int slotOf[12];
    uint32_t freem = 0xFFFu;
    #pragma unroll
    for (int e = 0; e < 12; ++e) {
      #pragma unroll
      for (int half = 0; half < 2; ++half) {
        if ((ln & 1) == half) {
          uint32_t b = (d[e] >> 2) & 31u;
          int best = 0; uint32_t bc = 0xFFFFFFFFu;
          #pragma unroll
          for (int k = 0; k < 12; ++k) {
            if ((freem >> k) & 1u) {
              uint32_t c = cnt[wv][k][b];
              if (c < bc) { bc = c; best = k; }
            }
          }
          slotOf[e] = best;
          freem &= ~(1u << best);
          atomicAdd(&cnt[wv][best][b], 1u);
        }
      }
    }
    // compose slot-ordered output (r1-proven format: 12 u16 addrs + 12x2b codes)
    uint32_t wv6[6]; uint32_t S = 0;
    #pragma unroll
    for (int k = 0; k < 12; ++k) {
      uint32_t de = 0, je = 0;
      #pragma unroll
      for (int e = 0; e < 12; ++e) {
        bool m = (slotOf[e] == k);
        de = m ? d[e] : de;
        je = m ? (uint32_t)(e / 3) : je;
      }
      if (k & 1) wv6[k >> 1] |= de << 16; else wv6[k >> 1] = de;
      S |= je << (2 * k);
    }
    uint4* o4 = (uint4*)(sched + (size_t)n * 8);
    o4[0] = make_uint4(wv6[0], wv6[1], wv6[2], wv6[3]);
    o4[1] = make_uint4(wv6[4], wv6[5], S, 0u);
    return;
  }

  // ================= in-OR + z-copy (r0-proven) =================
  const int t = blockIdx.x;
  const int es = (int)modep[0];
  unsigned char* zp = smem;                  // 4KB batch-packed z row
  uint32_t acc = 0;
  #pragma unroll
  for (int b = 0; b < B_; ++b) {
    uint32_t v4 = load4(z, ((long)b * T_ + t) * 1024 + n, es);
    acc |= v4 << b;
    ((uint4*)(out + ((long)b * T_ + t) * 8192))[n] = expand01(v4);
  }
  ((uint32_t*)zp)[n] = acc;
  __syncthreads();
  const uint4* ip = (const uint4*)(idxin + n * 12);
  uint4 q0 = ip[0], q1 = ip[1], q2 = ip[2];
  uint32_t r0 = (uint32_t)zp[q0.x] | zp[q0.y] | zp[q0.z];
  uint32_t r1 = (uint32_t)zp[q0.w] | zp[q1.x] | zp[q1.y];
  uint32_t r2 = (uint32_t)zp[q1.z] | zp[q1.w] | zp[q2.x];
  uint32_t r3 = (uint32_t)zp[q2.y] | zp[q2.z] | zp[q2.w];
  in_orb[t * 1024 + n] = r0 | (r1 << 8) | (r2 << 16) | (r3 << 24);
}

// ---------------- kernel 3: scheduled scan (r1-proven body, verbatim) --------
// 8 blocks, one per batch. Branch-free shift-OR over the conflict-minimized
// slot order; mask applied once (bytes are 0/1). 2-step unroll bakes the
// double-buffer phase into two address sets (aA / aB = aA+4096).
__global__ __launch_bounds__(1024) void scan_kernel(const uint32_t* __restrict__ in_orb,
                                                    const uint32_t* __restrict__ sched,
                                                    const void* __restrict__ h0,
                                                    const uint32_t* __restrict__ modep,
                                                    uint32_t* __restrict__ out) {
  const int b = blockIdx.x;
  const int n = threadIdx.x;
  const int es = (int)modep[0];
  __shared__ __align__(128) unsigned char hbuf[2][4096];

  const uint4* sp = (const uint4*)(sched + (size_t)n * 8);
  uint4 s0 = sp[0], s1 = sp[1];
  uint32_t aw[6] = { s0.x, s0.y, s0.z, s0.w, s1.x, s1.y };
  uint32_t aA[12], aB[12], sh[12];
  #pragma unroll
  for (int e = 0; e < 12; ++e) {
    uint32_t a = (aw[e >> 1] >> ((e & 1) * 16)) & 0xFFFFu;
    aA[e] = a; aB[e] = a + 4096u;
    sh[e] = ((s1.z >> (2 * e)) & 3u) * 8u;
  }

  unsigned char* lds8 = &hbuf[0][0];
  ((uint32_t*)lds8)[n] = load4(h0, (long)b * 1024 + n, es);
  __syncthreads();

  uint32_t* outh = out + (long)b * T_ * 8192 + 4096;

  uint32_t inw0 = in_orb[n];   // t = 0 (prefetched)
  for (int t = 0; t < T_; t += 2) {
    uint32_t inw1 = in_orb[(t + 1) * 1024 + n];
    // ---- step t: read buf0 (aA), write buf1
    uint32_t o = 0;
    #pragma unroll
    for (int e = 0; e < 12; ++e) o |= ((uint32_t)lds8[aA[e]]) << sh[e];
    o &= (inw0 >> b) & 0x01010101u;
    ((uint32_t*)(lds8 + 4096))[n] = o;
    ((uint4*)(outh + (long)t * 8192))[n] = expand01(o);      // fire-and-forget
    __syncthreads();
    uint32_t inw2 = (t + 2 < T_) ? in_orb[(t + 2) * 1024 + n] : 0u;
    // ---- step t+1: read buf1 (aB), write buf0
    uint32_t o2 = 0;
    #pragma unroll
    for (int e = 0; e < 12; ++e) o2 |= ((uint32_t)lds8[aB[e]]) << sh[e];
    o2 &= (inw1 >> b) & 0x01010101u;
    ((uint32_t*)lds8)[n] = o2;
    ((uint4*)(outh + (long)(t + 1) * 8192))[n] = expand01(o2);
    __syncthreads();
    inw0 = inw2;
  }
}

// ---------------- launch ----------------
extern "C" void kernel_launch(void* const* d_in, const int* in_sizes, int n_in,
                              void* d_out, int out_size, void* d_ws, size_t ws_size,
                              hipStream_t stream) {
  const void*  z   = d_in[0];                 // bool (B,T,CIN) - int32 0/1 (detected)
  const void*  h0  = d_in[1];                 // bool (B,CH)
  const float* Ain = (const float*)d_in[2];   // (CH,CIN) f32
  const float* Ah  = (const float*)d_in[3];   // (CH,CH)  f32
  uint32_t* out = (uint32_t*)d_out;           // int32 0/1

  char* ws = (char*)d_ws;
  // ws layout (bytes): [0] mode (256 res) | [256] idx_in 48K | [49408] idx_h 48K |
  //                    [98560] in_orb 4MiB | [4292864] sched 32K
  uint32_t* modep = (uint32_t*)(ws);
  uint32_t* idxin = (uint32_t*)(ws + 256);
  uint32_t* idxh  = (uint32_t*)(ws + 256 + 49152);
  uint32_t* inorb = (uint32_t*)(ws + 98560);
  uint32_t* schedp= (uint32_t*)(ws + 4292864);

  extract_kernel   <<<2049,   256,  0, stream>>>(Ain, Ah, idxin, idxh,
                                                 (const uint32_t*)z, modep);
  inor_sched_kernel<<<T_ + 1, 1024, 0, stream>>>(z, idxin, idxh, modep,
                                                 inorb, schedp, out);
  scan_kernel      <<<B_,     1024, 0, stream>>>(inorb, schedp, h0, modep, out);
}